// Round 1
// baseline (1095.694 us; speedup 1.0000x reference)
//
#include <hip/hip_runtime.h>

#define NNODES 65536
#define NDATA  32768
#define HID    128
#define HEADS  4
#define CHANS  32
#define LAYERS 4

__device__ __forceinline__ float wave_reduce_sum(float v) {
#pragma unroll
    for (int m = 1; m < 64; m <<= 1) v += __shfl_xor(v, m, 64);
    return v;
}

// ---------------- CSR build ----------------
__global__ void init_deg(int* __restrict__ deg) {
    int i = blockIdx.x * 256 + threadIdx.x;
    deg[i] = 1;  // self-loop
}

__global__ void hist_kernel(const int* __restrict__ ei, int* __restrict__ deg, int Eo) {
    int e = blockIdx.x * 256 + threadIdx.x;
    if (e >= Eo) return;
    atomicAdd(&deg[ei[Eo + e]], 1);   // dst row
}

__global__ void scan1(const int* __restrict__ deg, int* __restrict__ offs, int* __restrict__ bsum) {
    __shared__ int s[256];
    int t = threadIdx.x, b = blockIdx.x;
    int v = deg[b * 256 + t];
    s[t] = v;
    __syncthreads();
    for (int off = 1; off < 256; off <<= 1) {
        int add = (t >= off) ? s[t - off] : 0;
        __syncthreads();
        s[t] += add;
        __syncthreads();
    }
    offs[b * 256 + t] = s[t] - v;          // exclusive within block
    if (t == 255) bsum[b] = s[255];
}

__global__ void scan2(int* __restrict__ bsum) {
    __shared__ int s[256];
    int t = threadIdx.x;
    int v = bsum[t];
    s[t] = v;
    __syncthreads();
    for (int off = 1; off < 256; off <<= 1) {
        int add = (t >= off) ? s[t - off] : 0;
        __syncthreads();
        s[t] += add;
        __syncthreads();
    }
    bsum[t] = s[t] - v;                    // exclusive
}

__global__ void scan3(int* __restrict__ offs, const int* __restrict__ bsum,
                      int* __restrict__ cursor, int Eo) {
    int i = blockIdx.x * 256 + threadIdx.x;
    int v = offs[i] + bsum[i >> 8];
    offs[i] = v;
    cursor[i] = v;
    if (i == 0) offs[NNODES] = Eo + NNODES;
}

__global__ void fill_kernel(const int* __restrict__ ei, int* __restrict__ cursor,
                            int* __restrict__ col, int Eo) {
    int e = blockIdx.x * 256 + threadIdx.x;
    int Etot = Eo + NNODES;
    if (e >= Etot) return;
    int src, dst;
    if (e < Eo) { src = ei[e]; dst = ei[Eo + e]; }
    else        { src = dst = e - Eo; }
    int pos = atomicAdd(&cursor[dst], 1);
    col[pos] = src;
}

// ---------------- embedding + LN + ReLU (warp per node) ----------------
__global__ __launch_bounds__(256) void embed_kernel(
    const float* __restrict__ feat, const float* __restrict__ W,
    const float* __restrict__ bb, const float* __restrict__ g,
    const float* __restrict__ be, float* __restrict__ x)
{
    int node = blockIdx.x * 4 + (threadIdx.x >> 6);
    int lane = threadIdx.x & 63;
    float f[10];
#pragma unroll
    for (int i = 0; i < 10; i++) f[i] = feat[node * 10 + i];
    int c0 = lane, c1 = lane + 64;
    float v0 = bb[c0], v1 = bb[c1];
#pragma unroll
    for (int i = 0; i < 10; i++) {
        v0 = fmaf(f[i], W[i * HID + c0], v0);
        v1 = fmaf(f[i], W[i * HID + c1], v1);
    }
    float mu = wave_reduce_sum(v0 + v1) * (1.f / 128.f);
    float e0 = v0 - mu, e1 = v1 - mu;
    float var = wave_reduce_sum(e0 * e0 + e1 * e1) * (1.f / 128.f);
    float r = 1.f / sqrtf(var + 1e-5f);
    size_t xi = (size_t)node * HID;
    x[xi + c0] = fmaxf(e0 * r * g[c0] + be[c0], 0.f);
    x[xi + c1] = fmaxf(e1 * r * g[c1] + be[c1], 0.f);
}

// ---------------- tiled fp32 GEMM: C[M,NCOL] = A[M,K] @ B[K,NCOL] ----------------
template <int K, int NCOL, bool BIAS, bool RELU>
__global__ __launch_bounds__(256, 2) void gemm_kernel(
    const float* __restrict__ A, const float* __restrict__ B,
    const float* __restrict__ bias, float* __restrict__ C, int M)
{
    constexpr int BM = 64, BK = 32;
    constexpr int CPT = NCOL / 32;           // cols per thread
    __shared__ float As[BK][BM + 4];         // pad -> ~2-way (free) on staging writes
    __shared__ float Bs[BK][NCOL];
    int tid = threadIdx.x;
    int br = blockIdx.x * BM;
    int tx = tid & 31, ty = tid >> 5;
    int r0 = ty * 8, c0 = tx * CPT;
    float acc[8][CPT] = {};

    for (int kc = 0; kc < K; kc += BK) {
        // stage A tile (BM x BK), transposed into As[k][r]
#pragma unroll
        for (int p = 0; p < BM * BK / 4 / 256; ++p) {
            int idx = tid + p * 256;
            int r = idx >> 3;
            int kk = idx & 7;
            float4 v = *(const float4*)(A + (size_t)(br + r) * K + kc + kk * 4);
            As[kk * 4 + 0][r] = v.x; As[kk * 4 + 1][r] = v.y;
            As[kk * 4 + 2][r] = v.z; As[kk * 4 + 3][r] = v.w;
        }
        // stage B tile (BK x NCOL)
#pragma unroll
        for (int p = 0; p < BK * NCOL / 4 / 256; ++p) {
            int idx = tid + p * 256;
            int k = idx / (NCOL / 4);
            int c4 = idx % (NCOL / 4);
            *(float4*)&Bs[k][c4 * 4] = *(const float4*)(B + (size_t)(kc + k) * NCOL + c4 * 4);
        }
        __syncthreads();
#pragma unroll
        for (int k = 0; k < BK; k++) {
            float a[8];
            *(float4*)&a[0] = *(const float4*)&As[k][r0];
            *(float4*)&a[4] = *(const float4*)&As[k][r0 + 4];
            float bv[CPT];
            if constexpr (CPT == 4) {
                *(float4*)bv = *(const float4*)&Bs[k][c0];
            } else {
#pragma unroll
                for (int j = 0; j < CPT; j++) bv[j] = Bs[k][c0 + j];
            }
#pragma unroll
            for (int i = 0; i < 8; i++)
#pragma unroll
                for (int j = 0; j < CPT; j++)
                    acc[i][j] = fmaf(a[i], bv[j], acc[i][j]);
        }
        __syncthreads();
    }
#pragma unroll
    for (int i = 0; i < 8; i++) {
        float* crow = C + (size_t)(br + r0 + i) * NCOL + c0;
#pragma unroll
        for (int j = 0; j < CPT; j++) {
            float v = acc[i][j];
            if (BIAS) v += bias[c0 + j];
            if (RELU) v = fmaxf(v, 0.f);
            crow[j] = v;
        }
    }
}

// ---------------- attention scores a_s/a_d : [N, HEADS] ----------------
__global__ void att_kernel(const float* __restrict__ h, const float* __restrict__ ws_,
                           const float* __restrict__ wd_, float* __restrict__ a_s,
                           float* __restrict__ a_d)
{
    int t = blockIdx.x * 256 + threadIdx.x;    // t = node*4 + head
    if (t >= NNODES * HEADS) return;
    int head = t & 3;
    const float4* hp = (const float4*)(h + (size_t)t * CHANS);  // node*128 + head*32
    const float4* s4 = (const float4*)(ws_ + head * CHANS);
    const float4* d4 = (const float4*)(wd_ + head * CHANS);
    float ss = 0.f, sd = 0.f;
#pragma unroll
    for (int i = 0; i < 8; i++) {
        float4 v = hp[i], sv = s4[i], dv = d4[i];
        ss += v.x * sv.x + v.y * sv.y + v.z * sv.z + v.w * sv.w;
        sd += v.x * dv.x + v.y * dv.y + v.z * dv.z + v.w * dv.w;
    }
    a_s[t] = ss;
    a_d[t] = sd;
}

// ------- fused: per-dst softmax + weighted aggregate + bias + ReLU + residual + LN -------
__global__ __launch_bounds__(256) void gat_agg(
    const float* __restrict__ h, const float* __restrict__ a_s,
    const float* __restrict__ a_d, const int* __restrict__ offs,
    const int* __restrict__ col, const float* __restrict__ bgl,
    const float* __restrict__ gl, const float* __restrict__ bl,
    float* __restrict__ x)
{
    int node = blockIdx.x * 4 + (threadIdx.x >> 6);
    int lane = threadIdx.x & 63;
    int s = offs[node], e = offs[node + 1];
    float4 ad = *(const float4*)(a_d + (size_t)node * 4);

    // online softmax stats per head (redundant across lanes; wave-uniform)
    float m0 = -1e30f, m1 = -1e30f, m2 = -1e30f, m3 = -1e30f;
    float d0 = 0.f, d1 = 0.f, d2 = 0.f, d3 = 0.f;
    for (int j = s; j < e; j++) {
        int src = col[j];
        float4 as = *(const float4*)(a_s + (size_t)src * 4);
        float a0 = as.x + ad.x; a0 = (a0 > 0.f) ? a0 : 0.2f * a0;
        float a1 = as.y + ad.y; a1 = (a1 > 0.f) ? a1 : 0.2f * a1;
        float a2 = as.z + ad.z; a2 = (a2 > 0.f) ? a2 : 0.2f * a2;
        float a3 = as.w + ad.w; a3 = (a3 > 0.f) ? a3 : 0.2f * a3;
        d0 = (a0 > m0) ? (d0 * expf(m0 - a0) + 1.f) : (d0 + expf(a0 - m0)); m0 = fmaxf(m0, a0);
        d1 = (a1 > m1) ? (d1 * expf(m1 - a1) + 1.f) : (d1 + expf(a1 - m1)); m1 = fmaxf(m1, a1);
        d2 = (a2 > m2) ? (d2 * expf(m2 - a2) + 1.f) : (d2 + expf(a2 - m2)); m2 = fmaxf(m2, a2);
        d3 = (a3 > m3) ? (d3 * expf(m3 - a3) + 1.f) : (d3 + expf(a3 - m3)); m3 = fmaxf(m3, a3);
    }

    int c0 = lane, c1 = lane + 64;
    bool hi = (lane >= 32);                 // head(c0)=hi?1:0, head(c1)=hi?3:2
    float mm0 = hi ? m1 : m0, dd0 = hi ? d1 : d0;
    float mm1 = hi ? m3 : m2, dd1 = hi ? d3 : d2;
    float inv0 = 1.f / (dd0 + 1e-16f), inv1 = 1.f / (dd1 + 1e-16f);
    float acc0 = 0.f, acc1 = 0.f;
    for (int j = s; j < e; j++) {
        int src = col[j];
        float4 as = *(const float4*)(a_s + (size_t)src * 4);
        float s0 = hi ? (as.y + ad.y) : (as.x + ad.x); s0 = (s0 > 0.f) ? s0 : 0.2f * s0;
        float s1 = hi ? (as.w + ad.w) : (as.z + ad.z); s1 = (s1 > 0.f) ? s1 : 0.2f * s1;
        float w0 = expf(s0 - mm0) * inv0;
        float w1 = expf(s1 - mm1) * inv1;
        const float* hr = h + (size_t)src * HID;
        acc0 = fmaf(w0, hr[c0], acc0);
        acc1 = fmaf(w1, hr[c1], acc1);
    }

    // epilogue: + bias, ReLU, residual, LayerNorm (in place on x)
    float o0 = fmaxf(acc0 + bgl[c0], 0.f);
    float o1 = fmaxf(acc1 + bgl[c1], 0.f);
    size_t xi = (size_t)node * HID;
    float t0 = x[xi + c0] + o0;
    float t1 = x[xi + c1] + o1;
    float mu = wave_reduce_sum(t0 + t1) * (1.f / 128.f);
    float e0 = t0 - mu, e1 = t1 - mu;
    float var = wave_reduce_sum(e0 * e0 + e1 * e1) * (1.f / 128.f);
    float r = 1.f / sqrtf(var + 1e-5f);
    x[xi + c0] = e0 * r * gl[c0] + bl[c0];
    x[xi + c1] = e1 * r * gl[c1] + bl[c1];
}

// ---------------- policy final layer: [NDATA,64] @ [64,2] ----------------
__global__ void policy3_kernel(const float* __restrict__ h2, const float* __restrict__ W,
                               const float* __restrict__ b, float* __restrict__ out)
{
    int rr = blockIdx.x * 256 + threadIdx.x;
    if (rr >= NDATA) return;
    const float* hr = h2 + (size_t)rr * 64;
    float o0 = b[0], o1 = b[1];
#pragma unroll
    for (int k = 0; k < 64; k++) {
        float v = hr[k];
        o0 = fmaf(v, W[k * 2 + 0], o0);
        o1 = fmaf(v, W[k * 2 + 1], o1);
    }
    out[rr * 2 + 0] = o0;
    out[rr * 2 + 1] = o1;
}

// ---------------- value head ----------------
__global__ void pool_zero(float* __restrict__ pool) { pool[threadIdx.x] = 0.f; }

__global__ void pool_sum(const float* __restrict__ x, float* __restrict__ pool) {
    int t = threadIdx.x;                 // 128 threads
    int base = blockIdx.x * 256;         // 256 nodes per block
    float s = 0.f;
    for (int i = 0; i < 256; i++) s += x[(size_t)(base + i) * HID + t];
    atomicAdd(&pool[t], s);
}

__global__ void value_mlp(const float* __restrict__ pool,
                          const float* __restrict__ W1, const float* __restrict__ b1,
                          const float* __restrict__ W2, const float* __restrict__ b2,
                          const float* __restrict__ W3, const float* __restrict__ b3,
                          float* __restrict__ out)
{
    __shared__ float p[128], h1[128], h2[64];
    int t = threadIdx.x;
    p[t] = pool[t] * (1.f / (float)NNODES);
    __syncthreads();
    float a = b1[t];
    for (int k = 0; k < 128; k++) a = fmaf(p[k], W1[k * 128 + t], a);
    h1[t] = fmaxf(a, 0.f);
    __syncthreads();
    if (t < 64) {
        float a2 = b2[t];
        for (int k = 0; k < 128; k++) a2 = fmaf(h1[k], W2[k * 64 + t], a2);
        h2[t] = fmaxf(a2, 0.f);
    }
    __syncthreads();
    if (t == 0) {
        float v = b3[0];
        for (int k = 0; k < 64; k++) v = fmaf(h2[k], W3[k], v);
        out[NDATA * 2] = v;
    }
}

extern "C" void kernel_launch(void* const* d_in, const int* in_sizes, int n_in,
                              void* d_out, int out_size, void* d_ws, size_t ws_size,
                              hipStream_t stream)
{
    const float* feat  = (const float*)d_in[0];
    const int*   ei    = (const int*)d_in[1];
    const float* W_emb = (const float*)d_in[2];
    const float* b_emb = (const float*)d_in[3];
    const float* ln0g  = (const float*)d_in[4];
    const float* ln0b  = (const float*)d_in[5];
    const float* Wg    = (const float*)d_in[6];
    const float* att_s = (const float*)d_in[7];
    const float* att_d = (const float*)d_in[8];
    const float* bg    = (const float*)d_in[9];
    const float* lng   = (const float*)d_in[10];
    const float* lnb   = (const float*)d_in[11];
    const float* pW1 = (const float*)d_in[12]; const float* pb1 = (const float*)d_in[13];
    const float* pW2 = (const float*)d_in[14]; const float* pb2 = (const float*)d_in[15];
    const float* pW3 = (const float*)d_in[16]; const float* pb3 = (const float*)d_in[17];
    const float* vW1 = (const float*)d_in[18]; const float* vb1 = (const float*)d_in[19];
    const float* vW2 = (const float*)d_in[20]; const float* vb2 = (const float*)d_in[21];
    const float* vW3 = (const float*)d_in[22]; const float* vb3 = (const float*)d_in[23];
    float* out = (float*)d_out;
    int Eo = in_sizes[1] / 2;

    // workspace layout
    float* x    = (float*)d_ws;
    float* h    = x + (size_t)NNODES * HID;
    float* a_s  = h + (size_t)NNODES * HID;
    float* a_d  = a_s + NNODES * HEADS;
    int* deg    = (int*)(a_d + NNODES * HEADS);
    int* offs   = deg + NNODES;
    int* cursor = offs + NNODES + 2;
    int* bsum   = cursor + NNODES;
    int* col    = bsum + 256;
    float* pool = (float*)(col + Eo + NNODES);
    float* ph1  = h;                               // reuse h after GAT layers
    float* ph2  = h + (size_t)NDATA * HID;

    // CSR build (dst -> src list), self-loops included
    init_deg<<<NNODES / 256, 256, 0, stream>>>(deg);
    hist_kernel<<<(Eo + 255) / 256, 256, 0, stream>>>(ei, deg, Eo);
    scan1<<<256, 256, 0, stream>>>(deg, offs, bsum);
    scan2<<<1, 256, 0, stream>>>(bsum);
    scan3<<<256, 256, 0, stream>>>(offs, bsum, cursor, Eo);
    fill_kernel<<<(Eo + NNODES + 255) / 256, 256, 0, stream>>>(ei, cursor, col, Eo);

    // embedding
    embed_kernel<<<NNODES / 4, 256, 0, stream>>>(feat, W_emb, b_emb, ln0g, ln0b, x);

    // GAT layers
    for (int l = 0; l < LAYERS; l++) {
        gemm_kernel<128, 128, false, false><<<NNODES / 64, 256, 0, stream>>>(
            x, Wg + (size_t)l * HID * HID, nullptr, h, NNODES);
        att_kernel<<<NNODES * HEADS / 256, 256, 0, stream>>>(
            h, att_s + l * HEADS * CHANS, att_d + l * HEADS * CHANS, a_s, a_d);
        gat_agg<<<NNODES / 4, 256, 0, stream>>>(
            h, a_s, a_d, offs, col, bg + l * HID, lng + l * HID, lnb + l * HID, x);
    }

    // policy head (rows 0..NDATA-1)
    gemm_kernel<128, 128, true, true><<<NDATA / 64, 256, 0, stream>>>(x, pW1, pb1, ph1, NDATA);
    gemm_kernel<128, 64, true, true><<<NDATA / 64, 256, 0, stream>>>(ph1, pW2, pb2, ph2, NDATA);
    policy3_kernel<<<(NDATA + 255) / 256, 256, 0, stream>>>(ph2, pW3, pb3, out);

    // value head
    pool_zero<<<1, 128, 0, stream>>>(pool);
    pool_sum<<<256, 128, 0, stream>>>(x, pool);
    value_mlp<<<1, 128, 0, stream>>>(pool, vW1, vb1, vW2, vb2, vW3, vb3, out);
}

// Round 2
// 559.909 us; speedup vs baseline: 1.9569x; 1.9569x over previous
//
#include <hip/hip_runtime.h>

#define NNODES 65536
#define NDATA  32768
#define HID    128
#define HEADS  4
#define CHANS  32
#define LAYERS 4

__device__ __forceinline__ float wave_reduce_sum(float v) {
#pragma unroll
    for (int m = 1; m < 64; m <<= 1) v += __shfl_xor(v, m, 64);
    return v;
}

// ---------------- CSR build ----------------
__global__ void init_deg(int* __restrict__ deg) {
    int i = blockIdx.x * 256 + threadIdx.x;
    deg[i] = 1;  // self-loop
}

__global__ void hist_kernel(const int* __restrict__ ei, int* __restrict__ deg, int Eo) {
    int e = blockIdx.x * 256 + threadIdx.x;
    if (e >= Eo) return;
    atomicAdd(&deg[ei[Eo + e]], 1);   // dst row
}

__global__ void scan1(const int* __restrict__ deg, int* __restrict__ offs, int* __restrict__ bsum) {
    __shared__ int s[256];
    int t = threadIdx.x, b = blockIdx.x;
    int v = deg[b * 256 + t];
    s[t] = v;
    __syncthreads();
    for (int off = 1; off < 256; off <<= 1) {
        int add = (t >= off) ? s[t - off] : 0;
        __syncthreads();
        s[t] += add;
        __syncthreads();
    }
    offs[b * 256 + t] = s[t] - v;          // exclusive within block
    if (t == 255) bsum[b] = s[255];
}

__global__ void scan2(int* __restrict__ bsum) {
    __shared__ int s[256];
    int t = threadIdx.x;
    int v = bsum[t];
    s[t] = v;
    __syncthreads();
    for (int off = 1; off < 256; off <<= 1) {
        int add = (t >= off) ? s[t - off] : 0;
        __syncthreads();
        s[t] += add;
        __syncthreads();
    }
    bsum[t] = s[t] - v;                    // exclusive
}

__global__ void scan3(int* __restrict__ offs, const int* __restrict__ bsum,
                      int* __restrict__ cursor, int Eo) {
    int i = blockIdx.x * 256 + threadIdx.x;
    int v = offs[i] + bsum[i >> 8];
    offs[i] = v;
    cursor[i] = v;
    if (i == 0) offs[NNODES] = Eo + NNODES;
}

__global__ void fill_kernel(const int* __restrict__ ei, int* __restrict__ cursor,
                            int* __restrict__ col, int Eo) {
    int e = blockIdx.x * 256 + threadIdx.x;
    int Etot = Eo + NNODES;
    if (e >= Etot) return;
    int src, dst;
    if (e < Eo) { src = ei[e]; dst = ei[Eo + e]; }
    else        { src = dst = e - Eo; }
    int pos = atomicAdd(&cursor[dst], 1);
    col[pos] = src;
}

// ---------------- embedding + LN + ReLU (warp per node) ----------------
__global__ __launch_bounds__(256) void embed_kernel(
    const float* __restrict__ feat, const float* __restrict__ W,
    const float* __restrict__ bb, const float* __restrict__ g,
    const float* __restrict__ be, float* __restrict__ x)
{
    int node = blockIdx.x * 4 + (threadIdx.x >> 6);
    int lane = threadIdx.x & 63;
    float f[10];
#pragma unroll
    for (int i = 0; i < 10; i++) f[i] = feat[node * 10 + i];
    int c0 = lane, c1 = lane + 64;
    float v0 = bb[c0], v1 = bb[c1];
#pragma unroll
    for (int i = 0; i < 10; i++) {
        v0 = fmaf(f[i], W[i * HID + c0], v0);
        v1 = fmaf(f[i], W[i * HID + c1], v1);
    }
    float mu = wave_reduce_sum(v0 + v1) * (1.f / 128.f);
    float e0 = v0 - mu, e1 = v1 - mu;
    float var = wave_reduce_sum(e0 * e0 + e1 * e1) * (1.f / 128.f);
    float r = 1.f / sqrtf(var + 1e-5f);
    size_t xi = (size_t)node * HID;
    x[xi + c0] = fmaxf(e0 * r * g[c0] + be[c0], 0.f);
    x[xi + c1] = fmaxf(e1 * r * g[c1] + be[c1], 0.f);
}

// ---------------- tiled fp32 GEMM: C[M,NCOL] = A[M,K] @ B[K,NCOL] ----------------
template <int K, int NCOL, bool BIAS, bool RELU>
__global__ __launch_bounds__(256, 2) void gemm_kernel(
    const float* __restrict__ A, const float* __restrict__ B,
    const float* __restrict__ bias, float* __restrict__ C, int M)
{
    constexpr int BM = 64, BK = 32;
    constexpr int CPT = NCOL / 32;           // cols per thread
    __shared__ float As[BK][BM + 4];
    __shared__ float Bs[BK][NCOL];
    int tid = threadIdx.x;
    int br = blockIdx.x * BM;
    int tx = tid & 31, ty = tid >> 5;
    int r0 = ty * 8, c0 = tx * CPT;
    float acc[8][CPT] = {};

    for (int kc = 0; kc < K; kc += BK) {
#pragma unroll
        for (int p = 0; p < BM * BK / 4 / 256; ++p) {
            int idx = tid + p * 256;
            int r = idx >> 3;
            int kk = idx & 7;
            float4 v = *(const float4*)(A + (size_t)(br + r) * K + kc + kk * 4);
            As[kk * 4 + 0][r] = v.x; As[kk * 4 + 1][r] = v.y;
            As[kk * 4 + 2][r] = v.z; As[kk * 4 + 3][r] = v.w;
        }
#pragma unroll
        for (int p = 0; p < BK * NCOL / 4 / 256; ++p) {
            int idx = tid + p * 256;
            int k = idx / (NCOL / 4);
            int c4 = idx % (NCOL / 4);
            *(float4*)&Bs[k][c4 * 4] = *(const float4*)(B + (size_t)(kc + k) * NCOL + c4 * 4);
        }
        __syncthreads();
#pragma unroll
        for (int k = 0; k < BK; k++) {
            float a[8];
            *(float4*)&a[0] = *(const float4*)&As[k][r0];
            *(float4*)&a[4] = *(const float4*)&As[k][r0 + 4];
            float bv[CPT];
            if constexpr (CPT == 4) {
                *(float4*)bv = *(const float4*)&Bs[k][c0];
            } else {
#pragma unroll
                for (int j = 0; j < CPT; j++) bv[j] = Bs[k][c0 + j];
            }
#pragma unroll
            for (int i = 0; i < 8; i++)
#pragma unroll
                for (int j = 0; j < CPT; j++)
                    acc[i][j] = fmaf(a[i], bv[j], acc[i][j]);
        }
        __syncthreads();
    }
#pragma unroll
    for (int i = 0; i < 8; i++) {
        float* crow = C + (size_t)(br + r0 + i) * NCOL + c0;
#pragma unroll
        for (int j = 0; j < CPT; j++) {
            float v = acc[i][j];
            if (BIAS) v += bias[c0 + j];
            if (RELU) v = fmaxf(v, 0.f);
            crow[j] = v;
        }
    }
}

// ---------------- attention scores a_s/a_d : [N, HEADS] ----------------
__global__ void att_kernel(const float* __restrict__ h, const float* __restrict__ ws_,
                           const float* __restrict__ wd_, float* __restrict__ a_s,
                           float* __restrict__ a_d)
{
    int t = blockIdx.x * 256 + threadIdx.x;    // t = node*4 + head
    if (t >= NNODES * HEADS) return;
    int head = t & 3;
    const float4* hp = (const float4*)(h + (size_t)t * CHANS);  // node*128 + head*32
    const float4* s4 = (const float4*)(ws_ + head * CHANS);
    const float4* d4 = (const float4*)(wd_ + head * CHANS);
    float ss = 0.f, sd = 0.f;
#pragma unroll
    for (int i = 0; i < 8; i++) {
        float4 v = hp[i], sv = s4[i], dv = d4[i];
        ss += v.x * sv.x + v.y * sv.y + v.z * sv.z + v.w * sv.w;
        sd += v.x * dv.x + v.y * dv.y + v.z * dv.z + v.w * dv.w;
    }
    a_s[t] = ss;
    a_d[t] = sd;
}

// ------- fused: per-dst softmax + weighted aggregate + bias + ReLU + residual + LN -------
// Lane-parallel over edges; channels c0=2*lane, c1=2*lane+1 so each lane needs ONE head
// weight (head = lane>>4) and one float2 gather per edge.
__global__ __launch_bounds__(256) void gat_agg(
    const float* __restrict__ h, const float* __restrict__ a_s,
    const float* __restrict__ a_d, const int* __restrict__ offs,
    const int* __restrict__ col, const float* __restrict__ bgl,
    const float* __restrict__ gl, const float* __restrict__ bl,
    float* __restrict__ x)
{
    __shared__ float wsm[4][64][4];
    __shared__ int   ssm[4][64];
    int wv = threadIdx.x >> 6;
    int lane = threadIdx.x & 63;
    int node = blockIdx.x * 4 + wv;
    int s = offs[node], e = offs[node + 1];
    int deg = e - s;
    float4 ad = *(const float4*)(a_d + (size_t)node * 4);

    int c0 = 2 * lane, c1 = 2 * lane + 1;
    int head = lane >> 4;
    float acc0 = 0.f, acc1 = 0.f;

    if (deg <= 64) {
        // ---- fast path: one lane per edge ----
        int src = 0;
        float sc0 = -1e30f, sc1 = -1e30f, sc2 = -1e30f, sc3 = -1e30f;
        if (lane < deg) {
            src = col[s + lane];
            float4 as = *(const float4*)(a_s + (size_t)src * 4);
            sc0 = as.x + ad.x; sc0 = (sc0 > 0.f) ? sc0 : 0.2f * sc0;
            sc1 = as.y + ad.y; sc1 = (sc1 > 0.f) ? sc1 : 0.2f * sc1;
            sc2 = as.z + ad.z; sc2 = (sc2 > 0.f) ? sc2 : 0.2f * sc2;
            sc3 = as.w + ad.w; sc3 = (sc3 > 0.f) ? sc3 : 0.2f * sc3;
        }
        float m0 = sc0, m1 = sc1, m2 = sc2, m3 = sc3;
#pragma unroll
        for (int off = 1; off < 64; off <<= 1) {
            m0 = fmaxf(m0, __shfl_xor(m0, off, 64));
            m1 = fmaxf(m1, __shfl_xor(m1, off, 64));
            m2 = fmaxf(m2, __shfl_xor(m2, off, 64));
            m3 = fmaxf(m3, __shfl_xor(m3, off, 64));
        }
        // inactive lanes: sc = -1e30 -> exp() = 0, contributes nothing
        float e0 = expf(sc0 - m0), e1 = expf(sc1 - m1);
        float e2 = expf(sc2 - m2), e3 = expf(sc3 - m3);
        float d0 = e0, d1 = e1, d2 = e2, d3 = e3;
#pragma unroll
        for (int off = 1; off < 64; off <<= 1) {
            d0 += __shfl_xor(d0, off, 64);
            d1 += __shfl_xor(d1, off, 64);
            d2 += __shfl_xor(d2, off, 64);
            d3 += __shfl_xor(d3, off, 64);
        }
        float i0 = 1.f / (d0 + 1e-16f), i1 = 1.f / (d1 + 1e-16f);
        float i2 = 1.f / (d2 + 1e-16f), i3 = 1.f / (d3 + 1e-16f);
        *(float4*)&wsm[wv][lane][0] = make_float4(e0 * i0, e1 * i1, e2 * i2, e3 * i3);
        ssm[wv][lane] = src;
        // same-wave LDS RAW: no __syncthreads needed
        for (int j = 0; j < deg; j++) {
            int sj = ssm[wv][j];
            float wj = wsm[wv][j][head];
            float2 hv = *(const float2*)(h + (size_t)sj * HID + c0);
            acc0 = fmaf(wj, hv.x, acc0);
            acc1 = fmaf(wj, hv.y, acc1);
        }
    } else {
        // ---- rare fallback (deg > 64): serial, correctness-only ----
        float m0 = -1e30f, m1 = -1e30f, m2 = -1e30f, m3 = -1e30f;
        float d0 = 0.f, d1 = 0.f, d2 = 0.f, d3 = 0.f;
        for (int j = s; j < e; j++) {
            int src = col[j];
            float4 as = *(const float4*)(a_s + (size_t)src * 4);
            float a0 = as.x + ad.x; a0 = (a0 > 0.f) ? a0 : 0.2f * a0;
            float a1 = as.y + ad.y; a1 = (a1 > 0.f) ? a1 : 0.2f * a1;
            float a2 = as.z + ad.z; a2 = (a2 > 0.f) ? a2 : 0.2f * a2;
            float a3 = as.w + ad.w; a3 = (a3 > 0.f) ? a3 : 0.2f * a3;
            d0 = (a0 > m0) ? (d0 * expf(m0 - a0) + 1.f) : (d0 + expf(a0 - m0)); m0 = fmaxf(m0, a0);
            d1 = (a1 > m1) ? (d1 * expf(m1 - a1) + 1.f) : (d1 + expf(a1 - m1)); m1 = fmaxf(m1, a1);
            d2 = (a2 > m2) ? (d2 * expf(m2 - a2) + 1.f) : (d2 + expf(a2 - m2)); m2 = fmaxf(m2, a2);
            d3 = (a3 > m3) ? (d3 * expf(m3 - a3) + 1.f) : (d3 + expf(a3 - m3)); m3 = fmaxf(m3, a3);
        }
        float mh = (head == 0) ? m0 : (head == 1) ? m1 : (head == 2) ? m2 : m3;
        float dh = (head == 0) ? d0 : (head == 1) ? d1 : (head == 2) ? d2 : d3;
        float ih = 1.f / (dh + 1e-16f);
        for (int j = s; j < e; j++) {
            int src = col[j];
            float4 as = *(const float4*)(a_s + (size_t)src * 4);
            float sh = (head == 0) ? (as.x + ad.x) : (head == 1) ? (as.y + ad.y)
                     : (head == 2) ? (as.z + ad.z) : (as.w + ad.w);
            sh = (sh > 0.f) ? sh : 0.2f * sh;
            float wj = expf(sh - mh) * ih;
            float2 hv = *(const float2*)(h + (size_t)src * HID + c0);
            acc0 = fmaf(wj, hv.x, acc0);
            acc1 = fmaf(wj, hv.y, acc1);
        }
    }

    // epilogue: + bias, ReLU, residual, LayerNorm (in place on x)
    float o0 = fmaxf(acc0 + bgl[c0], 0.f);
    float o1 = fmaxf(acc1 + bgl[c1], 0.f);
    size_t xi = (size_t)node * HID;
    float2 xv = *(const float2*)(x + xi + c0);
    float t0 = xv.x + o0;
    float t1 = xv.y + o1;
    float mu = wave_reduce_sum(t0 + t1) * (1.f / 128.f);
    float e0 = t0 - mu, e1 = t1 - mu;
    float var = wave_reduce_sum(e0 * e0 + e1 * e1) * (1.f / 128.f);
    float r = 1.f / sqrtf(var + 1e-5f);
    float2 ov;
    ov.x = e0 * r * gl[c0] + bl[c0];
    ov.y = e1 * r * gl[c1] + bl[c1];
    *(float2*)(x + xi + c0) = ov;
}

// ---------------- policy final layer: [NDATA,64] @ [64,2] ----------------
__global__ void policy3_kernel(const float* __restrict__ h2, const float* __restrict__ W,
                               const float* __restrict__ b, float* __restrict__ out)
{
    int rr = blockIdx.x * 256 + threadIdx.x;
    if (rr >= NDATA) return;
    const float* hr = h2 + (size_t)rr * 64;
    float o0 = b[0], o1 = b[1];
#pragma unroll
    for (int k = 0; k < 64; k++) {
        float v = hr[k];
        o0 = fmaf(v, W[k * 2 + 0], o0);
        o1 = fmaf(v, W[k * 2 + 1], o1);
    }
    out[rr * 2 + 0] = o0;
    out[rr * 2 + 1] = o1;
}

// ---------------- value head ----------------
__global__ void pool_zero(float* __restrict__ pool) { pool[threadIdx.x] = 0.f; }

__global__ void pool_sum(const float* __restrict__ x, float* __restrict__ pool) {
    int t = threadIdx.x;                 // 128 threads
    int base = blockIdx.x * 256;         // 256 nodes per block
    float s = 0.f;
    for (int i = 0; i < 256; i++) s += x[(size_t)(base + i) * HID + t];
    atomicAdd(&pool[t], s);
}

__global__ void value_mlp(const float* __restrict__ pool,
                          const float* __restrict__ W1, const float* __restrict__ b1,
                          const float* __restrict__ W2, const float* __restrict__ b2,
                          const float* __restrict__ W3, const float* __restrict__ b3,
                          float* __restrict__ out)
{
    __shared__ float p[128], h1[128], h2[64];
    int t = threadIdx.x;
    p[t] = pool[t] * (1.f / (float)NNODES);
    __syncthreads();
    float a = b1[t];
    for (int k = 0; k < 128; k++) a = fmaf(p[k], W1[k * 128 + t], a);
    h1[t] = fmaxf(a, 0.f);
    __syncthreads();
    if (t < 64) {
        float a2 = b2[t];
        for (int k = 0; k < 128; k++) a2 = fmaf(h1[k], W2[k * 64 + t], a2);
        h2[t] = fmaxf(a2, 0.f);
    }
    __syncthreads();
    if (t == 0) {
        float v = b3[0];
        for (int k = 0; k < 64; k++) v = fmaf(h2[k], W3[k], v);
        out[NDATA * 2] = v;
    }
}

extern "C" void kernel_launch(void* const* d_in, const int* in_sizes, int n_in,
                              void* d_out, int out_size, void* d_ws, size_t ws_size,
                              hipStream_t stream)
{
    const float* feat  = (const float*)d_in[0];
    const int*   ei    = (const int*)d_in[1];
    const float* W_emb = (const float*)d_in[2];
    const float* b_emb = (const float*)d_in[3];
    const float* ln0g  = (const float*)d_in[4];
    const float* ln0b  = (const float*)d_in[5];
    const float* Wg    = (const float*)d_in[6];
    const float* att_s = (const float*)d_in[7];
    const float* att_d = (const float*)d_in[8];
    const float* bg    = (const float*)d_in[9];
    const float* lng   = (const float*)d_in[10];
    const float* lnb   = (const float*)d_in[11];
    const float* pW1 = (const float*)d_in[12]; const float* pb1 = (const float*)d_in[13];
    const float* pW2 = (const float*)d_in[14]; const float* pb2 = (const float*)d_in[15];
    const float* pW3 = (const float*)d_in[16]; const float* pb3 = (const float*)d_in[17];
    const float* vW1 = (const float*)d_in[18]; const float* vb1 = (const float*)d_in[19];
    const float* vW2 = (const float*)d_in[20]; const float* vb2 = (const float*)d_in[21];
    const float* vW3 = (const float*)d_in[22]; const float* vb3 = (const float*)d_in[23];
    float* out = (float*)d_out;
    int Eo = in_sizes[1] / 2;

    // workspace layout
    float* x    = (float*)d_ws;
    float* h    = x + (size_t)NNODES * HID;
    float* a_s  = h + (size_t)NNODES * HID;
    float* a_d  = a_s + NNODES * HEADS;
    int* deg    = (int*)(a_d + NNODES * HEADS);
    int* offs   = deg + NNODES;
    int* cursor = offs + NNODES + 2;
    int* bsum   = cursor + NNODES;
    int* col    = bsum + 256;
    float* pool = (float*)(col + Eo + NNODES);
    float* ph1  = h;                               // reuse h after GAT layers
    float* ph2  = h + (size_t)NDATA * HID;

    // CSR build (dst -> src list), self-loops included
    init_deg<<<NNODES / 256, 256, 0, stream>>>(deg);
    hist_kernel<<<(Eo + 255) / 256, 256, 0, stream>>>(ei, deg, Eo);
    scan1<<<256, 256, 0, stream>>>(deg, offs, bsum);
    scan2<<<1, 256, 0, stream>>>(bsum);
    scan3<<<256, 256, 0, stream>>>(offs, bsum, cursor, Eo);
    fill_kernel<<<(Eo + NNODES + 255) / 256, 256, 0, stream>>>(ei, cursor, col, Eo);

    // embedding
    embed_kernel<<<NNODES / 4, 256, 0, stream>>>(feat, W_emb, b_emb, ln0g, ln0b, x);

    // GAT layers
    for (int l = 0; l < LAYERS; l++) {
        gemm_kernel<128, 128, false, false><<<NNODES / 64, 256, 0, stream>>>(
            x, Wg + (size_t)l * HID * HID, nullptr, h, NNODES);
        att_kernel<<<NNODES * HEADS / 256, 256, 0, stream>>>(
            h, att_s + l * HEADS * CHANS, att_d + l * HEADS * CHANS, a_s, a_d);
        gat_agg<<<NNODES / 4, 256, 0, stream>>>(
            h, a_s, a_d, offs, col, bg + l * HID, lng + l * HID, lnb + l * HID, x);
    }

    // policy head (rows 0..NDATA-1)
    gemm_kernel<128, 128, true, true><<<NDATA / 64, 256, 0, stream>>>(x, pW1, pb1, ph1, NDATA);
    gemm_kernel<128, 64, true, true><<<NDATA / 64, 256, 0, stream>>>(ph1, pW2, pb2, ph2, NDATA);
    policy3_kernel<<<(NDATA + 255) / 256, 256, 0, stream>>>(ph2, pW3, pb3, out);

    // value head
    pool_zero<<<1, 128, 0, stream>>>(pool);
    pool_sum<<<256, 128, 0, stream>>>(x, pool);
    value_mlp<<<1, 128, 0, stream>>>(pool, vW1, vb1, vW2, vb2, vW3, vb3, out);
}

// Round 3
// 489.610 us; speedup vs baseline: 2.2379x; 1.1436x over previous
//
#include <hip/hip_runtime.h>

#define NNODES 65536
#define NDATA  32768
#define HID    128
#define HEADS  4
#define CHANS  32
#define LAYERS 4

__device__ __forceinline__ float wave_reduce_sum(float v) {
#pragma unroll
    for (int m = 1; m < 64; m <<= 1) v += __shfl_xor(v, m, 64);
    return v;
}

__device__ __forceinline__ unsigned short bf16_rne(float f) {
    unsigned u = __float_as_uint(f);
    return (unsigned short)((u + 0x7fffu + ((u >> 16) & 1u)) >> 16);
}

// ---------------- CSR build ----------------
__global__ void init_deg(int* __restrict__ deg) {
    int i = blockIdx.x * 256 + threadIdx.x;
    deg[i] = 1;  // self-loop
}

__global__ void hist_kernel(const int* __restrict__ ei, int* __restrict__ deg, int Eo) {
    int e = blockIdx.x * 256 + threadIdx.x;
    if (e >= Eo) return;
    atomicAdd(&deg[ei[Eo + e]], 1);   // dst row
}

__global__ void scan1(const int* __restrict__ deg, int* __restrict__ offs, int* __restrict__ bsum) {
    __shared__ int s[256];
    int t = threadIdx.x, b = blockIdx.x;
    int v = deg[b * 256 + t];
    s[t] = v;
    __syncthreads();
    for (int off = 1; off < 256; off <<= 1) {
        int add = (t >= off) ? s[t - off] : 0;
        __syncthreads();
        s[t] += add;
        __syncthreads();
    }
    offs[b * 256 + t] = s[t] - v;          // exclusive within block
    if (t == 255) bsum[b] = s[255];
}

__global__ void scan2(int* __restrict__ bsum) {
    __shared__ int s[256];
    int t = threadIdx.x;
    int v = bsum[t];
    s[t] = v;
    __syncthreads();
    for (int off = 1; off < 256; off <<= 1) {
        int add = (t >= off) ? s[t - off] : 0;
        __syncthreads();
        s[t] += add;
        __syncthreads();
    }
    bsum[t] = s[t] - v;                    // exclusive
}

__global__ void scan3(int* __restrict__ offs, const int* __restrict__ bsum,
                      int* __restrict__ cursor, int Eo) {
    int i = blockIdx.x * 256 + threadIdx.x;
    int v = offs[i] + bsum[i >> 8];
    offs[i] = v;
    cursor[i] = v;
    if (i == 0) offs[NNODES] = Eo + NNODES;
}

__global__ void fill_kernel(const int* __restrict__ ei, int* __restrict__ cursor,
                            int* __restrict__ col, int Eo) {
    int e = blockIdx.x * 256 + threadIdx.x;
    int Etot = Eo + NNODES;
    if (e >= Etot) return;
    int src, dst;
    if (e < Eo) { src = ei[e]; dst = ei[Eo + e]; }
    else        { src = dst = e - Eo; }
    int pos = atomicAdd(&cursor[dst], 1);
    col[pos] = src;
}

// ---------------- embedding + LN + ReLU (warp per node) ----------------
__global__ __launch_bounds__(256) void embed_kernel(
    const float* __restrict__ feat, const float* __restrict__ W,
    const float* __restrict__ bb, const float* __restrict__ g,
    const float* __restrict__ be, float* __restrict__ x)
{
    int node = blockIdx.x * 4 + (threadIdx.x >> 6);
    int lane = threadIdx.x & 63;
    float f[10];
#pragma unroll
    for (int i = 0; i < 10; i++) f[i] = feat[node * 10 + i];
    int c0 = lane, c1 = lane + 64;
    float v0 = bb[c0], v1 = bb[c1];
#pragma unroll
    for (int i = 0; i < 10; i++) {
        v0 = fmaf(f[i], W[i * HID + c0], v0);
        v1 = fmaf(f[i], W[i * HID + c1], v1);
    }
    float mu = wave_reduce_sum(v0 + v1) * (1.f / 128.f);
    float e0 = v0 - mu, e1 = v1 - mu;
    float var = wave_reduce_sum(e0 * e0 + e1 * e1) * (1.f / 128.f);
    float r = 1.f / sqrtf(var + 1e-5f);
    size_t xi = (size_t)node * HID;
    x[xi + c0] = fmaxf(e0 * r * g[c0] + be[c0], 0.f);
    x[xi + c1] = fmaxf(e1 * r * g[c1] + be[c1], 0.f);
}

// -------- GAT GEMM: h_bf16[M,128] = x[M,128] @ Wg[128,128]; fused a_s/a_d epilogue --------
__global__ __launch_bounds__(256, 2) void gemm_gat(
    const float* __restrict__ A, const float* __restrict__ B,
    const float* __restrict__ attS, const float* __restrict__ attD,
    unsigned short* __restrict__ hb, float* __restrict__ a_s, float* __restrict__ a_d)
{
    constexpr int K = 128, NCOL = 128, BM = 64, BK = 32;
    __shared__ float As[BK][BM + 4];
    __shared__ float Bs[BK][NCOL];
    int tid = threadIdx.x;
    int br = blockIdx.x * BM;
    int tx = tid & 31, ty = tid >> 5;
    int r0 = ty * 8, c0 = tx * 4;
    float acc[8][4] = {};

    for (int kc = 0; kc < K; kc += BK) {
#pragma unroll
        for (int p = 0; p < BM * BK / 4 / 256; ++p) {
            int idx = tid + p * 256;
            int r = idx >> 3;
            int kk = idx & 7;
            float4 v = *(const float4*)(A + (size_t)(br + r) * K + kc + kk * 4);
            As[kk * 4 + 0][r] = v.x; As[kk * 4 + 1][r] = v.y;
            As[kk * 4 + 2][r] = v.z; As[kk * 4 + 3][r] = v.w;
        }
#pragma unroll
        for (int p = 0; p < BK * NCOL / 4 / 256; ++p) {
            int idx = tid + p * 256;
            int k = idx / (NCOL / 4);
            int c4 = idx % (NCOL / 4);
            *(float4*)&Bs[k][c4 * 4] = *(const float4*)(B + (size_t)(kc + k) * NCOL + c4 * 4);
        }
        __syncthreads();
#pragma unroll
        for (int k = 0; k < BK; k++) {
            float a[8];
            *(float4*)&a[0] = *(const float4*)&As[k][r0];
            *(float4*)&a[4] = *(const float4*)&As[k][r0 + 4];
            float4 bv = *(const float4*)&Bs[k][c0];
#pragma unroll
            for (int i = 0; i < 8; i++) {
                acc[i][0] = fmaf(a[i], bv.x, acc[i][0]);
                acc[i][1] = fmaf(a[i], bv.y, acc[i][1]);
                acc[i][2] = fmaf(a[i], bv.z, acc[i][2]);
                acc[i][3] = fmaf(a[i], bv.w, acc[i][3]);
            }
        }
        __syncthreads();
    }

    // epilogue: bf16 h store + per-head attention score partial reduce
    int hh = tx >> 3;                       // head of this thread's 4 cols
    float4 ws4 = *(const float4*)(attS + hh * CHANS + (tx & 7) * 4);
    float4 wd4 = *(const float4*)(attD + hh * CHANS + (tx & 7) * 4);
#pragma unroll
    for (int i = 0; i < 8; i++) {
        int row = br + r0 + i;
        ushort4 hv;
        hv.x = bf16_rne(acc[i][0]); hv.y = bf16_rne(acc[i][1]);
        hv.z = bf16_rne(acc[i][2]); hv.w = bf16_rne(acc[i][3]);
        *(ushort4*)(hb + (size_t)row * HID + c0) = hv;
        float ps = acc[i][0] * ws4.x + acc[i][1] * ws4.y + acc[i][2] * ws4.z + acc[i][3] * ws4.w;
        float pd = acc[i][0] * wd4.x + acc[i][1] * wd4.y + acc[i][2] * wd4.z + acc[i][3] * wd4.w;
        ps += __shfl_xor(ps, 1, 64); pd += __shfl_xor(pd, 1, 64);
        ps += __shfl_xor(ps, 2, 64); pd += __shfl_xor(pd, 2, 64);
        ps += __shfl_xor(ps, 4, 64); pd += __shfl_xor(pd, 4, 64);
        if ((tx & 7) == 0) {
            a_s[row * 4 + hh] = ps;
            a_d[row * 4 + hh] = pd;
        }
    }
}

// ---------------- generic tiled fp32 GEMM (policy head) ----------------
template <int K, int NCOL, bool BIAS, bool RELU>
__global__ __launch_bounds__(256, 2) void gemm_kernel(
    const float* __restrict__ A, const float* __restrict__ B,
    const float* __restrict__ bias, float* __restrict__ C, int M)
{
    constexpr int BM = 64, BK = 32;
    constexpr int CPT = NCOL / 32;           // cols per thread
    __shared__ float As[BK][BM + 4];
    __shared__ float Bs[BK][NCOL];
    int tid = threadIdx.x;
    int br = blockIdx.x * BM;
    int tx = tid & 31, ty = tid >> 5;
    int r0 = ty * 8, c0 = tx * CPT;
    float acc[8][CPT] = {};

    for (int kc = 0; kc < K; kc += BK) {
#pragma unroll
        for (int p = 0; p < BM * BK / 4 / 256; ++p) {
            int idx = tid + p * 256;
            int r = idx >> 3;
            int kk = idx & 7;
            float4 v = *(const float4*)(A + (size_t)(br + r) * K + kc + kk * 4);
            As[kk * 4 + 0][r] = v.x; As[kk * 4 + 1][r] = v.y;
            As[kk * 4 + 2][r] = v.z; As[kk * 4 + 3][r] = v.w;
        }
#pragma unroll
        for (int p = 0; p < BK * NCOL / 4 / 256; ++p) {
            int idx = tid + p * 256;
            int k = idx / (NCOL / 4);
            int c4 = idx % (NCOL / 4);
            *(float4*)&Bs[k][c4 * 4] = *(const float4*)(B + (size_t)(kc + k) * NCOL + c4 * 4);
        }
        __syncthreads();
#pragma unroll
        for (int k = 0; k < BK; k++) {
            float a[8];
            *(float4*)&a[0] = *(const float4*)&As[k][r0];
            *(float4*)&a[4] = *(const float4*)&As[k][r0 + 4];
            float bv[CPT];
            if constexpr (CPT == 4) {
                *(float4*)bv = *(const float4*)&Bs[k][c0];
            } else {
#pragma unroll
                for (int j = 0; j < CPT; j++) bv[j] = Bs[k][c0 + j];
            }
#pragma unroll
            for (int i = 0; i < 8; i++)
#pragma unroll
                for (int j = 0; j < CPT; j++)
                    acc[i][j] = fmaf(a[i], bv[j], acc[i][j]);
        }
        __syncthreads();
    }
#pragma unroll
    for (int i = 0; i < 8; i++) {
        float* crow = C + (size_t)(br + r0 + i) * NCOL + c0;
#pragma unroll
        for (int j = 0; j < CPT; j++) {
            float v = acc[i][j];
            if (BIAS) v += bias[c0 + j];
            if (RELU) v = fmaxf(v, 0.f);
            crow[j] = v;
        }
    }
}

// ------- fused: per-dst softmax + weighted aggregate (bf16 h) + bias/ReLU/residual/LN -------
__global__ __launch_bounds__(256) void gat_agg(
    const unsigned short* __restrict__ hb, const float* __restrict__ a_s,
    const float* __restrict__ a_d, const int* __restrict__ offs,
    const int* __restrict__ col, const float* __restrict__ bgl,
    const float* __restrict__ gl, const float* __restrict__ bl,
    float* __restrict__ x)
{
    __shared__ float wsm[4][64][4];
    __shared__ int   ssm[4][64];
    int wv = threadIdx.x >> 6;
    int lane = threadIdx.x & 63;
    int node = blockIdx.x * 4 + wv;
    int s = offs[node], e = offs[node + 1];
    int deg = e - s;
    float4 ad = *(const float4*)(a_d + (size_t)node * 4);

    int c0 = 2 * lane, c1 = 2 * lane + 1;
    int head = lane >> 4;
    float acc0 = 0.f, acc1 = 0.f;

    if (deg <= 64) {
        // ---- fast path: one lane per edge ----
        int src = 0;
        float sc0 = -1e30f, sc1 = -1e30f, sc2 = -1e30f, sc3 = -1e30f;
        if (lane < deg) {
            src = col[s + lane];
            float4 as = *(const float4*)(a_s + (size_t)src * 4);
            sc0 = as.x + ad.x; sc0 = (sc0 > 0.f) ? sc0 : 0.2f * sc0;
            sc1 = as.y + ad.y; sc1 = (sc1 > 0.f) ? sc1 : 0.2f * sc1;
            sc2 = as.z + ad.z; sc2 = (sc2 > 0.f) ? sc2 : 0.2f * sc2;
            sc3 = as.w + ad.w; sc3 = (sc3 > 0.f) ? sc3 : 0.2f * sc3;
        }
        float m0 = sc0, m1 = sc1, m2 = sc2, m3 = sc3;
#pragma unroll
        for (int off = 1; off < 64; off <<= 1) {
            m0 = fmaxf(m0, __shfl_xor(m0, off, 64));
            m1 = fmaxf(m1, __shfl_xor(m1, off, 64));
            m2 = fmaxf(m2, __shfl_xor(m2, off, 64));
            m3 = fmaxf(m3, __shfl_xor(m3, off, 64));
        }
        float e0 = expf(sc0 - m0), e1 = expf(sc1 - m1);
        float e2 = expf(sc2 - m2), e3 = expf(sc3 - m3);
        float d0 = e0, d1 = e1, d2 = e2, d3 = e3;
#pragma unroll
        for (int off = 1; off < 64; off <<= 1) {
            d0 += __shfl_xor(d0, off, 64);
            d1 += __shfl_xor(d1, off, 64);
            d2 += __shfl_xor(d2, off, 64);
            d3 += __shfl_xor(d3, off, 64);
        }
        float i0 = 1.f / (d0 + 1e-16f), i1 = 1.f / (d1 + 1e-16f);
        float i2 = 1.f / (d2 + 1e-16f), i3 = 1.f / (d3 + 1e-16f);
        *(float4*)&wsm[wv][lane][0] = make_float4(e0 * i0, e1 * i1, e2 * i2, e3 * i3);
        ssm[wv][lane] = src;
        // same-wave LDS RAW: no __syncthreads needed
        for (int j = 0; j < deg; j++) {
            int sj = ssm[wv][j];
            float wj = wsm[wv][j][head];
            unsigned hv = *(const unsigned*)(hb + (((unsigned)sj << 7) + (unsigned)c0));
            float h0 = __uint_as_float(hv << 16);
            float h1 = __uint_as_float(hv & 0xffff0000u);
            acc0 = fmaf(wj, h0, acc0);
            acc1 = fmaf(wj, h1, acc1);
        }
    } else {
        // ---- rare fallback (deg > 64): serial, correctness-only ----
        float m0 = -1e30f, m1 = -1e30f, m2 = -1e30f, m3 = -1e30f;
        float d0 = 0.f, d1 = 0.f, d2 = 0.f, d3 = 0.f;
        for (int j = s; j < e; j++) {
            int src = col[j];
            float4 as = *(const float4*)(a_s + (size_t)src * 4);
            float a0 = as.x + ad.x; a0 = (a0 > 0.f) ? a0 : 0.2f * a0;
            float a1 = as.y + ad.y; a1 = (a1 > 0.f) ? a1 : 0.2f * a1;
            float a2 = as.z + ad.z; a2 = (a2 > 0.f) ? a2 : 0.2f * a2;
            float a3 = as.w + ad.w; a3 = (a3 > 0.f) ? a3 : 0.2f * a3;
            d0 = (a0 > m0) ? (d0 * expf(m0 - a0) + 1.f) : (d0 + expf(a0 - m0)); m0 = fmaxf(m0, a0);
            d1 = (a1 > m1) ? (d1 * expf(m1 - a1) + 1.f) : (d1 + expf(a1 - m1)); m1 = fmaxf(m1, a1);
            d2 = (a2 > m2) ? (d2 * expf(m2 - a2) + 1.f) : (d2 + expf(a2 - m2)); m2 = fmaxf(m2, a2);
            d3 = (a3 > m3) ? (d3 * expf(m3 - a3) + 1.f) : (d3 + expf(a3 - m3)); m3 = fmaxf(m3, a3);
        }
        float mh = (head == 0) ? m0 : (head == 1) ? m1 : (head == 2) ? m2 : m3;
        float dh = (head == 0) ? d0 : (head == 1) ? d1 : (head == 2) ? d2 : d3;
        float ih = 1.f / (dh + 1e-16f);
        for (int j = s; j < e; j++) {
            int src = col[j];
            float4 as = *(const float4*)(a_s + (size_t)src * 4);
            float sh = (head == 0) ? (as.x + ad.x) : (head == 1) ? (as.y + ad.y)
                     : (head == 2) ? (as.z + ad.z) : (as.w + ad.w);
            sh = (sh > 0.f) ? sh : 0.2f * sh;
            float wj = expf(sh - mh) * ih;
            unsigned hv = *(const unsigned*)(hb + (((unsigned)src << 7) + (unsigned)c0));
            float h0 = __uint_as_float(hv << 16);
            float h1 = __uint_as_float(hv & 0xffff0000u);
            acc0 = fmaf(wj, h0, acc0);
            acc1 = fmaf(wj, h1, acc1);
        }
    }

    // epilogue: + bias, ReLU, residual, LayerNorm (in place on x)
    float o0 = fmaxf(acc0 + bgl[c0], 0.f);
    float o1 = fmaxf(acc1 + bgl[c1], 0.f);
    size_t xi = (size_t)node * HID;
    float2 xv = *(const float2*)(x + xi + c0);
    float t0 = xv.x + o0;
    float t1 = xv.y + o1;
    float mu = wave_reduce_sum(t0 + t1) * (1.f / 128.f);
    float e0 = t0 - mu, e1 = t1 - mu;
    float var = wave_reduce_sum(e0 * e0 + e1 * e1) * (1.f / 128.f);
    float r = 1.f / sqrtf(var + 1e-5f);
    float2 ov;
    ov.x = e0 * r * gl[c0] + bl[c0];
    ov.y = e1 * r * gl[c1] + bl[c1];
    *(float2*)(x + xi + c0) = ov;
}

// ---------------- policy final layer: [NDATA,64] @ [64,2] ----------------
__global__ void policy3_kernel(const float* __restrict__ h2, const float* __restrict__ W,
                               const float* __restrict__ b, float* __restrict__ out)
{
    int rr = blockIdx.x * 256 + threadIdx.x;
    if (rr >= NDATA) return;
    const float* hr = h2 + (size_t)rr * 64;
    float o0 = b[0], o1 = b[1];
#pragma unroll
    for (int k = 0; k < 64; k++) {
        float v = hr[k];
        o0 = fmaf(v, W[k * 2 + 0], o0);
        o1 = fmaf(v, W[k * 2 + 1], o1);
    }
    out[rr * 2 + 0] = o0;
    out[rr * 2 + 1] = o1;
}

// ---------------- value head ----------------
__global__ void pool_zero(float* __restrict__ pool) { pool[threadIdx.x] = 0.f; }

__global__ void pool_sum(const float* __restrict__ x, float* __restrict__ pool) {
    int t = threadIdx.x;                 // 128 threads
    int base = blockIdx.x * 256;         // 256 nodes per block
    float s = 0.f;
    for (int i = 0; i < 256; i++) s += x[(size_t)(base + i) * HID + t];
    atomicAdd(&pool[t], s);
}

__global__ void value_mlp(const float* __restrict__ pool,
                          const float* __restrict__ W1, const float* __restrict__ b1,
                          const float* __restrict__ W2, const float* __restrict__ b2,
                          const float* __restrict__ W3, const float* __restrict__ b3,
                          float* __restrict__ out)
{
    __shared__ float p[128], h1[128], h2[64];
    int t = threadIdx.x;
    p[t] = pool[t] * (1.f / (float)NNODES);
    __syncthreads();
    float a = b1[t];
    for (int k = 0; k < 128; k++) a = fmaf(p[k], W1[k * 128 + t], a);
    h1[t] = fmaxf(a, 0.f);
    __syncthreads();
    if (t < 64) {
        float a2 = b2[t];
        for (int k = 0; k < 128; k++) a2 = fmaf(h1[k], W2[k * 64 + t], a2);
        h2[t] = fmaxf(a2, 0.f);
    }
    __syncthreads();
    if (t == 0) {
        float v = b3[0];
        for (int k = 0; k < 64; k++) v = fmaf(h2[k], W3[k], v);
        out[NDATA * 2] = v;
    }
}

extern "C" void kernel_launch(void* const* d_in, const int* in_sizes, int n_in,
                              void* d_out, int out_size, void* d_ws, size_t ws_size,
                              hipStream_t stream)
{
    const float* feat  = (const float*)d_in[0];
    const int*   ei    = (const int*)d_in[1];
    const float* W_emb = (const float*)d_in[2];
    const float* b_emb = (const float*)d_in[3];
    const float* ln0g  = (const float*)d_in[4];
    const float* ln0b  = (const float*)d_in[5];
    const float* Wg    = (const float*)d_in[6];
    const float* att_s = (const float*)d_in[7];
    const float* att_d = (const float*)d_in[8];
    const float* bg    = (const float*)d_in[9];
    const float* lng   = (const float*)d_in[10];
    const float* lnb   = (const float*)d_in[11];
    const float* pW1 = (const float*)d_in[12]; const float* pb1 = (const float*)d_in[13];
    const float* pW2 = (const float*)d_in[14]; const float* pb2 = (const float*)d_in[15];
    const float* pW3 = (const float*)d_in[16]; const float* pb3 = (const float*)d_in[17];
    const float* vW1 = (const float*)d_in[18]; const float* vb1 = (const float*)d_in[19];
    const float* vW2 = (const float*)d_in[20]; const float* vb2 = (const float*)d_in[21];
    const float* vW3 = (const float*)d_in[22]; const float* vb3 = (const float*)d_in[23];
    float* out = (float*)d_out;
    int Eo = in_sizes[1] / 2;

    // workspace layout
    float* x             = (float*)d_ws;                         // 65536*128 f32
    unsigned short* hbuf = (unsigned short*)(x + (size_t)NNODES * HID);  // 65536*128 bf16
    float* ph1           = (float*)hbuf;                         // reused after GAT layers (same 16.8MB)
    float* ph2           = (float*)(hbuf + (size_t)NNODES * HID);        // 32768*64 f32
    float* a_s           = ph2 + (size_t)NDATA * 64;
    float* a_d           = a_s + NNODES * HEADS;
    int* deg    = (int*)(a_d + NNODES * HEADS);
    int* offs   = deg + NNODES;
    int* cursor = offs + NNODES + 2;
    int* bsum   = cursor + NNODES;
    int* col    = bsum + 256;
    float* pool = (float*)(col + Eo + NNODES);

    // CSR build (dst -> src list), self-loops included
    init_deg<<<NNODES / 256, 256, 0, stream>>>(deg);
    hist_kernel<<<(Eo + 255) / 256, 256, 0, stream>>>(ei, deg, Eo);
    scan1<<<256, 256, 0, stream>>>(deg, offs, bsum);
    scan2<<<1, 256, 0, stream>>>(bsum);
    scan3<<<256, 256, 0, stream>>>(offs, bsum, cursor, Eo);
    fill_kernel<<<(Eo + NNODES + 255) / 256, 256, 0, stream>>>(ei, cursor, col, Eo);

    // embedding
    embed_kernel<<<NNODES / 4, 256, 0, stream>>>(feat, W_emb, b_emb, ln0g, ln0b, x);

    // GAT layers
    for (int l = 0; l < LAYERS; l++) {
        gemm_gat<<<NNODES / 64, 256, 0, stream>>>(
            x, Wg + (size_t)l * HID * HID,
            att_s + l * HEADS * CHANS, att_d + l * HEADS * CHANS,
            hbuf, a_s, a_d);
        gat_agg<<<NNODES / 4, 256, 0, stream>>>(
            hbuf, a_s, a_d, offs, col, bg + l * HID, lng + l * HID, lnb + l * HID, x);
    }

    // policy head (rows 0..NDATA-1)
    gemm_kernel<128, 128, true, true><<<NDATA / 64, 256, 0, stream>>>(x, pW1, pb1, ph1, NDATA);
    gemm_kernel<128, 64, true, true><<<NDATA / 64, 256, 0, stream>>>(ph1, pW2, pb2, ph2, NDATA);
    policy3_kernel<<<(NDATA + 255) / 256, 256, 0, stream>>>(ph2, pW3, pb3, out);

    // value head
    pool_zero<<<1, 128, 0, stream>>>(pool);
    pool_sum<<<256, 128, 0, stream>>>(x, pool);
    value_mlp<<<1, 128, 0, stream>>>(pool, vW1, vb1, vW2, vb2, vW3, vb3, out);
}